// Round 2
// baseline (14879.102 us; speedup 1.0000x reference)
//
#include <hip/hip_runtime.h>

using bf16x8 = __attribute__((ext_vector_type(8))) short;
using f32x4  = __attribute__((ext_vector_type(4))) float;
typedef unsigned short u16;
typedef unsigned int   u32;

// B=256, T=256, D=64, H=512, O=10
// Rings: 4-slot [256][512] bf16 planes (hi,lo) per layer. Slot = 1<<17 elems.
// 256 WGs x 256 thr: L=wg>>7, bt=(wg&127)>>3 (16 batches), nt8=wg&7 (64 n-cols).
// Wave ww (0..3) owns n0 = nt8*64 + ww*16 (one 16x16 MFMA tile), weights resident
// in VGPRs all 257 stages. Pipeline: stage s: L0 computes h0_s, L1 computes h1_{s-1}.
// Flags count to 8 producers per (stage, bt). Depth-4 rings; backpressure fl1[s-3].

__device__ __forceinline__ float bf2f(u16 u){ union{u32 i;float f;}v; v.i=((u32)u)<<16; return v.f; }
__device__ __forceinline__ u16 f2bf(float f){ union{float f;u32 i;}v; v.f=f; u32 x=v.i; return (u16)((x+0x7FFFu+((x>>16)&1u))>>16); }
__device__ __forceinline__ bf16x8 load8f(const float* p){
  bf16x8 r;
#pragma unroll
  for(int i=0;i<8;++i) r[i]=(short)f2bf(p[i]);
  return r;
}
__device__ __forceinline__ void wait_flag(int* p, int n){
  int it = 0;
  while (__hip_atomic_load(p, __ATOMIC_ACQUIRE, __HIP_MEMORY_SCOPE_AGENT) < n) {
    __builtin_amdgcn_s_sleep(2);
    if (++it > 20000) break;   // deadlock -> wrong answer (signal), not a hang
  }
}

__global__ void init_kernel(uint4* p){
  p[(size_t)blockIdx.x*512u + threadIdx.x] = make_uint4(0u,0u,0u,0u);
}

__global__ void __launch_bounds__(256,2)
rnn_kernel(const float* __restrict__ x,
           const float* __restrict__ w_ih0, const float* __restrict__ w_hh0,
           const float* __restrict__ b_ih0, const float* __restrict__ b_hh0,
           const float* __restrict__ w_ih1, const float* __restrict__ w_hh1,
           const float* __restrict__ b_ih1, const float* __restrict__ b_hh1,
           const float* __restrict__ fc1_w, const float* __restrict__ fc1_b,
           const float* __restrict__ fc2_w, const float* __restrict__ fc2_b,
           float* __restrict__ out,
           u16* __restrict__ h0hi, u16* __restrict__ h0lo,
           u16* __restrict__ h1hi, u16* __restrict__ h1lo,
           int* __restrict__ fl0, int* __restrict__ fl1)
{
  const int tid = threadIdx.x;
  const int wg  = blockIdx.x;
  const int lane= tid & 63;
  const int ww  = tid >> 6;       // 0..3
  const int L   = wg >> 7;
  const int gi  = wg & 127;
  const int bt  = gi >> 3;        // 0..15
  const int nt8 = gi & 7;         // 0..7
  const int b0  = bt << 4;
  const int n0  = (nt8 << 6) + (ww << 4);
  const int lrow= lane & 15;      // MFMA A-row / D-col
  const int lk8 = (lane >> 4) << 3;

  __shared__ char smAhi[16384], smAlo[16384];
  __shared__ char smBhi[16384], smBlo[16384];
  __shared__ char smXhi[2048],  smXlo[2048];
  __shared__ float smF[128];

  // ---- resident weight fragments (bf16). B-frag: lane holds W[n0+lrow][k0+lk8+j]
  bf16x8 wA[16], wB[16];
  float bias;
  {
    const int n = n0 + lrow;
    if (L == 0) {
#pragma unroll
      for (int c=0;c<16;++c) wA[c] = load8f(w_hh0 + n*512 + (c<<5) + lk8);
      wB[0] = load8f(w_ih0 + n*64 + lk8);
      wB[1] = load8f(w_ih0 + n*64 + 32 + lk8);
      bias = b_ih0[n] + b_hh0[n];
    } else {
#pragma unroll
      for (int c=0;c<16;++c) {
        wA[c] = load8f(w_ih1 + n*512 + (c<<5) + lk8);
        wB[c] = load8f(w_hh1 + n*512 + (c<<5) + lk8);
      }
      bias = b_ih1[n] + b_hh1[n];
    }
  }

  const int sw = (lrow & 7) << 4;
  const int ar = lrow << 10;

  for (int s = 0; s <= 256; ++s) {
    if (L == 0) {
      if (s < 256) {
        if (s >= 1) wait_flag(&fl0[((s-1)<<4)+bt], 8);
        if (s >= 4) wait_flag(&fl1[((s-3)<<4)+bt], 8);
        // stage h0_{s-1} (hi,lo) -> LDS with row-XOR swizzle; x_s -> LDS split
        {
          const char* sh = (const char*)(h0hi + (((s-1)&3)<<17));
          const char* sl = (const char*)(h0lo + (((s-1)&3)<<17));
          int ib = tid << 4;
#pragma unroll
          for (int p=0;p<4;++p, ib+=4096) {
            int row = ib >> 10, col = ib & 1023;
            int so  = ((b0+row)<<10) + col;
            int dof = (row<<10) + (col ^ ((row&7)<<4));
            *(uint4*)(smAhi+dof) = *(const uint4*)(sh+so);
            *(uint4*)(smAlo+dof) = *(const uint4*)(sl+so);
          }
          int idx = tid << 2, xr = idx >> 6, xc = idx & 63;
          float4 xv = *(const float4*)(x + (((b0+xr)*256 + s)<<6) + xc);
          u16 h_, l_;
          u32 ph0, pl0, ph1, pl1;
          h_=f2bf(xv.x); l_=f2bf(xv.x-bf2f(h_)); ph0=h_;        pl0=l_;
          h_=f2bf(xv.y); l_=f2bf(xv.y-bf2f(h_)); ph0|=(u32)h_<<16; pl0|=(u32)l_<<16;
          h_=f2bf(xv.z); l_=f2bf(xv.z-bf2f(h_)); ph1=h_;        pl1=l_;
          h_=f2bf(xv.w); l_=f2bf(xv.w-bf2f(h_)); ph1|=(u32)h_<<16; pl1|=(u32)l_<<16;
          int xof = (xr<<7) + ((xc<<1) ^ ((xr&7)<<4));
          *(u32*)(smXhi+xof)   = ph0;  *(u32*)(smXhi+xof+4) = ph1;
          *(u32*)(smXlo+xof)   = pl0;  *(u32*)(smXlo+xof+4) = pl1;
        }
        __syncthreads();
        f32x4 acc = {0.f,0.f,0.f,0.f};
#pragma unroll
        for (int c=0;c<16;++c) {
          int off = ar + ((((c<<5)+lk8)<<1) ^ sw);
          acc = __builtin_amdgcn_mfma_f32_16x16x32_bf16(*(const bf16x8*)(smAhi+off), wA[c], acc, 0,0,0);
          acc = __builtin_amdgcn_mfma_f32_16x16x32_bf16(*(const bf16x8*)(smAlo+off), wA[c], acc, 0,0,0);
        }
#pragma unroll
        for (int c=0;c<2;++c) {
          int off = (lrow<<7) + ((((c<<5)+lk8)<<1) ^ sw);
          acc = __builtin_amdgcn_mfma_f32_16x16x32_bf16(*(const bf16x8*)(smXhi+off), wB[c], acc, 0,0,0);
          acc = __builtin_amdgcn_mfma_f32_16x16x32_bf16(*(const bf16x8*)(smXlo+off), wB[c], acc, 0,0,0);
        }
        {
          u32 base = ((u32)(s&3)<<17) + n0 + lrow;
          int rbase = b0 + ((lane>>4)<<2);
#pragma unroll
          for (int r=0;r<4;++r) {          // D: row=(lane>>4)*4+r, col=lrow
            float v = acc[r] + bias; v = v > 0.f ? v : 0.f;
            u16 hi = f2bf(v), lo = f2bf(v - bf2f(hi));
            h0hi[base + ((u32)(rbase+r)<<9)] = hi;
            h0lo[base + ((u32)(rbase+r)<<9)] = lo;
          }
        }
        __threadfence();
        __syncthreads();
        if (tid == 0)
          __hip_atomic_fetch_add(&fl0[(s<<4)+bt], 1, __ATOMIC_RELEASE, __HIP_MEMORY_SCOPE_AGENT);
      }
    } else {
      if (s >= 1) {
        wait_flag(&fl0[((s-1)<<4)+bt], 8);
        if (s >= 2) wait_flag(&fl1[((s-1)<<4)+bt], 8);
        {
          const char* ah = (const char*)(h0hi + (((s-1)&3)<<17));
          const char* al = (const char*)(h0lo + (((s-1)&3)<<17));
          const char* bh = (const char*)(h1hi + (((s-2)&3)<<17));
          const char* bl = (const char*)(h1lo + (((s-2)&3)<<17));
          int ib = tid << 4;
#pragma unroll
          for (int p=0;p<4;++p, ib+=4096) {
            int row = ib >> 10, col = ib & 1023;
            int so  = ((b0+row)<<10) + col;
            int dof = (row<<10) + (col ^ ((row&7)<<4));
            *(uint4*)(smAhi+dof) = *(const uint4*)(ah+so);
            *(uint4*)(smAlo+dof) = *(const uint4*)(al+so);
            *(uint4*)(smBhi+dof) = *(const uint4*)(bh+so);
            *(uint4*)(smBlo+dof) = *(const uint4*)(bl+so);
          }
        }
        __syncthreads();
        f32x4 acc = {0.f,0.f,0.f,0.f};
#pragma unroll
        for (int c=0;c<16;++c) {
          int off = ar + ((((c<<5)+lk8)<<1) ^ sw);
          acc = __builtin_amdgcn_mfma_f32_16x16x32_bf16(*(const bf16x8*)(smAhi+off), wA[c], acc, 0,0,0);
          acc = __builtin_amdgcn_mfma_f32_16x16x32_bf16(*(const bf16x8*)(smAlo+off), wA[c], acc, 0,0,0);
          acc = __builtin_amdgcn_mfma_f32_16x16x32_bf16(*(const bf16x8*)(smBhi+off), wB[c], acc, 0,0,0);
          acc = __builtin_amdgcn_mfma_f32_16x16x32_bf16(*(const bf16x8*)(smBlo+off), wB[c], acc, 0,0,0);
        }
        {
          u32 base = (((u32)((s-1)&3))<<17) + n0 + lrow;
          int rbase = b0 + ((lane>>4)<<2);
#pragma unroll
          for (int r=0;r<4;++r) {
            float v = acc[r] + bias; v = v > 0.f ? v : 0.f;
            u16 hi = f2bf(v), lo = f2bf(v - bf2f(hi));
            h1hi[base + ((u32)(rbase+r)<<9)] = hi;
            h1lo[base + ((u32)(rbase+r)<<9)] = lo;
          }
        }
        __threadfence();
        __syncthreads();
        if (tid == 0)
          __hip_atomic_fetch_add(&fl1[(s<<4)+bt], 1, __ATOMIC_RELEASE, __HIP_MEMORY_SCOPE_AGENT);
      }
    }
  }

  // ---- head: fc1(relu) + fc2 on h1_{255} (ring slot 3), one WG per bt ----
  if (L == 1 && nt8 == 0) {
    wait_flag(&fl1[(256<<4)+bt], 8);
    if (tid < 128) {
      int b = b0 + (tid >> 3), j = tid & 7;     // tid = (b-b0)*8 + j
      const u16* ph = h1hi + (3u<<17) + (b<<9);
      const u16* pl = h1lo + (3u<<17) + (b<<9);
      const float* wr = fc1_w + (j<<9);
      float acc = fc1_b[j];
#pragma unroll 4
      for (int kk=0; kk<64; ++kk) {
        uint4 vh = *(const uint4*)(ph + (kk<<3));
        uint4 vl = *(const uint4*)(pl + (kk<<3));
        const float* w8 = wr + (kk<<3);
        u32 ah[4] = {vh.x, vh.y, vh.z, vh.w};
        u32 al[4] = {vl.x, vl.y, vl.z, vl.w};
#pragma unroll
        for (int q=0;q<4;++q) {
          float e0 = bf2f((u16)ah[q]) + bf2f((u16)al[q]);
          float e1 = bf2f((u16)(ah[q]>>16)) + bf2f((u16)(al[q]>>16));
          acc += e0*w8[2*q] + e1*w8[2*q+1];
        }
      }
      smF[tid] = acc > 0.f ? acc : 0.f;
    }
    __syncthreads();
    if (tid < 160) {
      int bb = tid / 10, o = tid - bb*10;
      float acc = fc2_b[o];
      const float* w = fc2_w + o*8;
#pragma unroll
      for (int j=0;j<8;++j) acc += smF[bb*8+j]*w[j];
      out[(b0+bb)*10 + o] = acc;
    }
  }
}

extern "C" void kernel_launch(void* const* d_in, const int* in_sizes, int n_in,
                              void* d_out, int out_size, void* d_ws, size_t ws_size,
                              hipStream_t stream) {
  const float* x     = (const float*)d_in[0];
  const float* w_ih0 = (const float*)d_in[1];
  const float* w_hh0 = (const float*)d_in[2];
  const float* b_ih0 = (const float*)d_in[3];
  const float* b_hh0 = (const float*)d_in[4];
  const float* w_ih1 = (const float*)d_in[5];
  const float* w_hh1 = (const float*)d_in[6];
  const float* b_ih1 = (const float*)d_in[7];
  const float* b_hh1 = (const float*)d_in[8];
  const float* fc1_w = (const float*)d_in[9];
  const float* fc1_b = (const float*)d_in[10];
  const float* fc2_w = (const float*)d_in[11];
  const float* fc2_b = (const float*)d_in[12];
  float* out = (float*)d_out;

  char* ws = (char*)d_ws;
  u16* h0hi = (u16*)(ws + 0*(1<<20));
  u16* h0lo = (u16*)(ws + 1*(1<<20));
  u16* h1hi = (u16*)(ws + 2*(1<<20));
  u16* h1lo = (u16*)(ws + 3*(1<<20));
  int* fl0  = (int*)(ws + 4*(1<<20));
  int* fl1  = (int*)(ws + 4*(1<<20) + 32768);

  // zero rings + flags: (4 MB + 64 KB) / 16 B = 266240 uint4 = 520 * 512
  init_kernel<<<dim3(520), dim3(512), 0, stream>>>((uint4*)ws);
  rnn_kernel<<<dim3(256), dim3(256), 0, stream>>>(
      x, w_ih0, w_hh0, b_ih0, b_hh0, w_ih1, w_hh1, b_ih1, b_hh1,
      fc1_w, fc1_b, fc2_w, fc2_b, out,
      h0hi, h0lo, h1hi, h1lo, fl0, fl1);
}

// Round 3
// 1666.904 us; speedup vs baseline: 8.9262x; 8.9262x over previous
//
#include <hip/hip_runtime.h>

using bf16x8 = __attribute__((ext_vector_type(8))) short;
using f32x4  = __attribute__((ext_vector_type(4))) float;
typedef unsigned short u16;
typedef unsigned int   u32;
typedef unsigned long long u64;

#define MAX_SPIN 1000000

// B=256,T=256,D=64,H=512,O=10.
// 96 WGs x 512 thr, role = wg>>4 (0,1: L0 n-halves; 2..5: L1 n-quarters), bt = wg&15.
// Role-major ids => all 6 WGs of a bt share blockIdx%8 (likely same XCD; perf-only).
// Rings hold h as packed u32 = (bf16_hi<<16)|bf16_lo, 4 slots of [256][512].
// All cross-WG data/flag traffic = relaxed agent-scope atomics (IF-point ops,
// no buffer_wbl2/buffer_inv). Release = vmcnt(0) (via __syncthreads) + relaxed add.
// Pipeline: L0 stage s: h0_s = relu(W_ih0 x_s + W_hh0 h0_{s-1} + b)  [xproj overlapped
// with partner wait]; L1 stage t: h1_t = relu(W_ih1 h0_t + W_hh1 h1_{t-1} + b).
// Flags: fl0[s][bt] -> 2 producers; fl1[t][bt] -> 4 producers.
// Waits: L0(s): fl0[s-1]==2 (s>=1), fl1[s-4]==4 (s>=4, ring depth 4 backpressure).
//        L1(t): fl0[t]==2, fl1[t-1]==4 (t>=1).

__device__ __forceinline__ float bf2f(u16 u){ union{u32 i;float f;}v; v.i=((u32)u)<<16; return v.f; }
__device__ __forceinline__ u16 f2bf(float f){ union{float f;u32 i;}v; v.f=f; u32 x=v.i; return (u16)((x+0x7FFFu+((x>>16)&1u))>>16); }
__device__ __forceinline__ u32 packhl(float v){ u16 hi=f2bf(v); u16 lo=f2bf(v-bf2f(hi)); return ((u32)hi<<16)|(u32)lo; }
__device__ __forceinline__ bf16x8 load8f(const float* p){
  float4 a=*(const float4*)p; float4 b=*(const float4*)(p+4);
  bf16x8 r; r[0]=(short)f2bf(a.x); r[1]=(short)f2bf(a.y); r[2]=(short)f2bf(a.z); r[3]=(short)f2bf(a.w);
  r[4]=(short)f2bf(b.x); r[5]=(short)f2bf(b.y); r[6]=(short)f2bf(b.z); r[7]=(short)f2bf(b.w); return r;
}
__device__ __forceinline__ int  ldf(const int* p){ return __hip_atomic_load(p, __ATOMIC_RELAXED, __HIP_MEMORY_SCOPE_AGENT); }
__device__ __forceinline__ u64 ld64c(const u32* p){ return __hip_atomic_load((const u64*)p, __ATOMIC_RELAXED, __HIP_MEMORY_SCOPE_AGENT); }
__device__ __forceinline__ u32 ld32c(const u32* p){ return __hip_atomic_load(p, __ATOMIC_RELAXED, __HIP_MEMORY_SCOPE_AGENT); }
__device__ __forceinline__ void st32c(u32* p, u32 v){ __hip_atomic_store(p, v, __ATOMIC_RELAXED, __HIP_MEMORY_SCOPE_AGENT); }

__global__ void init_kernel(u32* p){  // zero flags (32 KB)
  p[(blockIdx.x<<9) + threadIdx.x] = 0u;
}

__global__ void __launch_bounds__(512, 2)
rnn_kernel(const float* __restrict__ x,
           const float* __restrict__ w_ih0, const float* __restrict__ w_hh0,
           const float* __restrict__ b_ih0, const float* __restrict__ b_hh0,
           const float* __restrict__ w_ih1, const float* __restrict__ w_hh1,
           const float* __restrict__ b_ih1, const float* __restrict__ b_hh1,
           const float* __restrict__ fc1_w, const float* __restrict__ fc1_b,
           const float* __restrict__ fc2_w, const float* __restrict__ fc2_b,
           float* __restrict__ out,
           u32* __restrict__ ring0, u32* __restrict__ ring1,
           int* __restrict__ fl0, int* __restrict__ fl1)
{
  const int tid  = threadIdx.x;
  const int wg   = blockIdx.x;        // 0..95
  const int lane = tid & 63;
  const int ww   = tid >> 6;          // 0..7
  const int role = wg >> 4;           // 0..5
  const int bt   = wg & 15;
  const int b0   = bt << 4;
  const int lrow = lane & 15;
  const int lk8  = (lane >> 4) << 3;
  const int sw   = (lrow & 7) << 4;

  __shared__ char smA[32768];         // hi plane @0, lo plane @16384 ([16][512] bf16)
  __shared__ char smB[32768];         // L1: h1 planes; L0: x planes ([16][64] bf16 @0 / @16384)

  if (role < 2) {
    // ================= L0: n-half [role*256, role*256+256) =================
    const int nbase = role << 8;
    bf16x8 wH0[16], wH1[16], wX0[2], wX1[2];
    float bias0, bias1;
    {
      const int n0c = nbase + (ww << 5) + lrow;        // tile t2=0
      const int n1c = n0c + 16;                        // tile t2=1
#pragma unroll
      for (int ks = 0; ks < 16; ++ks) {
        wH0[ks] = load8f(w_hh0 + n0c*512 + (ks<<5) + lk8);
        wH1[ks] = load8f(w_hh0 + n1c*512 + (ks<<5) + lk8);
      }
      wX0[0] = load8f(w_ih0 + n0c*64 + lk8);  wX0[1] = load8f(w_ih0 + n0c*64 + 32 + lk8);
      wX1[0] = load8f(w_ih0 + n1c*64 + lk8);  wX1[1] = load8f(w_ih0 + n1c*64 + 32 + lk8);
      bias0 = b_ih0[n0c] + b_hh0[n0c];
      bias1 = b_ih0[n1c] + b_hh0[n1c];
    }

    for (int s = 0; s < 256; ++s) {
      // ---- stage x_s -> LDS (plain cached loads; input is read-only) ----
      {
        int idx = tid << 1, r = idx >> 6, c = idx & 63;
        const float* xp = x + ((size_t)((b0 + r) << 8) + s) * 64 + c;
        float2 xv = *(const float2*)xp;
        u32 e0 = packhl(xv.x), e1 = packhl(xv.y);
        u32 hiw = (e0 >> 16) | (e1 & 0xFFFF0000u);
        u32 low = (e0 & 0xFFFFu) | (e1 << 16);
        int xo = (r << 7) + (((c << 1)) ^ ((r & 7) << 4));
        *(u32*)(smB + xo) = hiw;  *(u32*)(smB + 16384 + xo) = low;
      }
      __syncthreads();
      // ---- x-projection MFMAs (overlaps partner wait below) ----
      f32x4 acc0 = {0.f,0.f,0.f,0.f}, acc1 = {0.f,0.f,0.f,0.f};
#pragma unroll
      for (int ks = 0; ks < 2; ++ks) {
        int off = (lrow << 7) + (((ks << 6) + (lk8 << 1)) ^ sw);
        bf16x8 ahi = *(const bf16x8*)(smB + off);
        bf16x8 alo = *(const bf16x8*)(smB + 16384 + off);
        acc0 = __builtin_amdgcn_mfma_f32_16x16x32_bf16(ahi, wX0[ks], acc0, 0,0,0);
        acc0 = __builtin_amdgcn_mfma_f32_16x16x32_bf16(alo, wX0[ks], acc0, 0,0,0);
        acc1 = __builtin_amdgcn_mfma_f32_16x16x32_bf16(ahi, wX1[ks], acc1, 0,0,0);
        acc1 = __builtin_amdgcn_mfma_f32_16x16x32_bf16(alo, wX1[ks], acc1, 0,0,0);
      }
      // ---- wait: partner half of h0[s-1]; ring-slot backpressure ----
      if (ww == 0) {
        const int* f0p = fl0 + ((s - 1) << 4) + bt;
        const int* f1p = fl1 + ((s - 4) << 4) + bt;
        int it = 0;
        for (;;) {
          bool ok = true;
          if (s >= 1 && ldf(f0p) < 2) ok = false;
          if (ok && s >= 4 && ldf(f1p) < 4) ok = false;
          if (ok || ++it > MAX_SPIN) break;
        }
      }
      __syncthreads();
      if (s >= 1) {
        // ---- stage h0[s-1] (full 16x512) from ring0 slot (s-1)&3 ----
        const u32* rs = ring0 + (((s - 1) & 3) << 17) + (b0 << 9);
#pragma unroll
        for (int k = 0; k < 8; ++k) {
          int q = tid + (k << 9);          // pair index 0..4095
          int r = q >> 8, c = q & 255;
          u64 v = ld64c(rs + (r << 9) + (c << 1));
          u32 e0 = (u32)v, e1 = (u32)(v >> 32);
          u32 hiw = (e0 >> 16) | (e1 & 0xFFFF0000u);
          u32 low = (e0 & 0xFFFFu) | (e1 << 16);
          int o = (r << 10) + ((c << 2) ^ ((r & 7) << 4));
          *(u32*)(smA + o) = hiw;  *(u32*)(smA + 16384 + o) = low;
        }
        __syncthreads();
#pragma unroll
        for (int ks = 0; ks < 16; ++ks) {
          int off = (lrow << 10) + (((ks << 6) + (lk8 << 1)) ^ sw);
          bf16x8 ahi = *(const bf16x8*)(smA + off);
          bf16x8 alo = *(const bf16x8*)(smA + 16384 + off);
          acc0 = __builtin_amdgcn_mfma_f32_16x16x32_bf16(ahi, wH0[ks], acc0, 0,0,0);
          acc0 = __builtin_amdgcn_mfma_f32_16x16x32_bf16(alo, wH0[ks], acc0, 0,0,0);
          acc1 = __builtin_amdgcn_mfma_f32_16x16x32_bf16(ahi, wH1[ks], acc1, 0,0,0);
          acc1 = __builtin_amdgcn_mfma_f32_16x16x32_bf16(alo, wH1[ks], acc1, 0,0,0);
        }
      }
      // ---- store h0[s] (coherent), publish flag ----
      {
        u32* wsl = ring0 + ((s & 3) << 17) + (b0 << 9);
        int rr0 = (lane >> 4) << 2;
        int nc0 = nbase + (ww << 5) + lrow, nc1 = nc0 + 16;
#pragma unroll
        for (int r = 0; r < 4; ++r) {
          float v0 = acc0[r] + bias0; v0 = v0 > 0.f ? v0 : 0.f;
          float v1 = acc1[r] + bias1; v1 = v1 > 0.f ? v1 : 0.f;
          st32c(wsl + ((rr0 + r) << 9) + nc0, packhl(v0));
          st32c(wsl + ((rr0 + r) << 9) + nc1, packhl(v1));
        }
      }
      asm volatile("s_waitcnt vmcnt(0)" ::: "memory");
      __syncthreads();
      if (tid == 0)
        __hip_atomic_fetch_add(fl0 + (s << 4) + bt, 1, __ATOMIC_RELAXED, __HIP_MEMORY_SCOPE_AGENT);
    }
  } else {
    // ================= L1: n-quarter [(role-2)*128, +128) =================
    const int nbase = (role - 2) << 7;
    bf16x8 wI[16], wHH[16];
    float bias;
    {
      const int n = nbase + (ww << 4) + lrow;
#pragma unroll
      for (int ks = 0; ks < 16; ++ks) {
        wI[ks]  = load8f(w_ih1 + n*512 + (ks<<5) + lk8);
        wHH[ks] = load8f(w_hh1 + n*512 + (ks<<5) + lk8);
      }
      bias = b_ih1[n] + b_hh1[n];
    }

    for (int t = 0; t < 256; ++t) {
      if (ww == 0) {
        const int* f0p = fl0 + (t << 4) + bt;
        const int* f1p = fl1 + ((t - 1) << 4) + bt;
        int it = 0;
        for (;;) {
          bool ok = (ldf(f0p) >= 2);
          if (ok && t >= 1 && ldf(f1p) < 4) ok = false;
          if (ok || ++it > MAX_SPIN) break;
        }
      }
      __syncthreads();
      {
        const u32* ra = ring0 + ((t & 3) << 17) + (b0 << 9);
        const u32* rb = ring1 + (((t - 1) & 3) << 17) + (b0 << 9);
#pragma unroll
        for (int k = 0; k < 8; ++k) {
          int q = tid + (k << 9);
          int r = q >> 8, c = q & 255;
          int o = (r << 10) + ((c << 2) ^ ((r & 7) << 4));
          u64 v = ld64c(ra + (r << 9) + (c << 1));
          u32 e0 = (u32)v, e1 = (u32)(v >> 32);
          *(u32*)(smA + o)         = (e0 >> 16) | (e1 & 0xFFFF0000u);
          *(u32*)(smA + 16384 + o) = (e0 & 0xFFFFu) | (e1 << 16);
          if (t >= 1) {
            u64 w = ld64c(rb + (r << 9) + (c << 1));
            u32 f0v = (u32)w, f1v = (u32)(w >> 32);
            *(u32*)(smB + o)         = (f0v >> 16) | (f1v & 0xFFFF0000u);
            *(u32*)(smB + 16384 + o) = (f0v & 0xFFFFu) | (f1v << 16);
          }
        }
      }
      __syncthreads();
      f32x4 acc = {0.f,0.f,0.f,0.f};
      if (t == 0) {
#pragma unroll
        for (int ks = 0; ks < 16; ++ks) {
          int off = (lrow << 10) + (((ks << 6) + (lk8 << 1)) ^ sw);
          bf16x8 ahi = *(const bf16x8*)(smA + off);
          bf16x8 alo = *(const bf16x8*)(smA + 16384 + off);
          acc = __builtin_amdgcn_mfma_f32_16x16x32_bf16(ahi, wI[ks], acc, 0,0,0);
          acc = __builtin_amdgcn_mfma_f32_16x16x32_bf16(alo, wI[ks], acc, 0,0,0);
        }
      } else {
#pragma unroll
        for (int ks = 0; ks < 16; ++ks) {
          int off = (lrow << 10) + (((ks << 6) + (lk8 << 1)) ^ sw);
          bf16x8 ahi = *(const bf16x8*)(smA + off);
          bf16x8 alo = *(const bf16x8*)(smA + 16384 + off);
          bf16x8 bhi = *(const bf16x8*)(smB + off);
          bf16x8 blo = *(const bf16x8*)(smB + 16384 + off);
          acc = __builtin_amdgcn_mfma_f32_16x16x32_bf16(ahi, wI[ks],  acc, 0,0,0);
          acc = __builtin_amdgcn_mfma_f32_16x16x32_bf16(alo, wI[ks],  acc, 0,0,0);
          acc = __builtin_amdgcn_mfma_f32_16x16x32_bf16(bhi, wHH[ks], acc, 0,0,0);
          acc = __builtin_amdgcn_mfma_f32_16x16x32_bf16(blo, wHH[ks], acc, 0,0,0);
        }
      }
      {
        u32* wsl = ring1 + ((t & 3) << 17) + (b0 << 9);
        int rr0 = (lane >> 4) << 2;
        int nc = nbase + (ww << 4) + lrow;
#pragma unroll
        for (int r = 0; r < 4; ++r) {
          float v = acc[r] + bias; v = v > 0.f ? v : 0.f;
          st32c(wsl + ((rr0 + r) << 9) + nc, packhl(v));
        }
      }
      asm volatile("s_waitcnt vmcnt(0)" ::: "memory");
      __syncthreads();
      if (tid == 0)
        __hip_atomic_fetch_add(fl1 + (t << 4) + bt, 1, __ATOMIC_RELAXED, __HIP_MEMORY_SCOPE_AGENT);
    }

    // ================= head (role==2 WG per bt) =================
    if (role == 2) {
      if (ww == 0) {
        const int* fp = fl1 + (255 << 4) + bt;
        int it = 0;
        while (ldf(fp) < 4) { if (++it > MAX_SPIN) break; }
      }
      __syncthreads();
      float* smF = (float*)smA;
      if (tid < 128) {
        int b = b0 + (tid >> 3), j = tid & 7;
        const u32* hp = ring1 + (3 << 17) + (b << 9);
        const float* wr = fc1_w + (j << 9);
        float accv = fc1_b[j];
        for (int k = 0; k < 512; k += 2) {
          u64 v = ld64c(hp + k);
          u32 e0 = (u32)v, e1 = (u32)(v >> 32);
          float h0v = bf2f((u16)(e0 >> 16)) + bf2f((u16)(e0 & 0xFFFFu));
          float h1v = bf2f((u16)(e1 >> 16)) + bf2f((u16)(e1 & 0xFFFFu));
          accv += h0v * wr[k] + h1v * wr[k + 1];
        }
        smF[tid] = accv > 0.f ? accv : 0.f;
      }
      __syncthreads();
      if (tid < 160) {
        int bb = tid / 10, o = tid - bb * 10;
        float accv = fc2_b[o];
        const float* w = fc2_w + (o << 3);
#pragma unroll
        for (int j = 0; j < 8; ++j) accv += smF[(bb << 3) + j] * w[j];
        out[(b0 + bb) * 10 + o] = accv;
      }
    }
  }
}

extern "C" void kernel_launch(void* const* d_in, const int* in_sizes, int n_in,
                              void* d_out, int out_size, void* d_ws, size_t ws_size,
                              hipStream_t stream) {
  const float* x     = (const float*)d_in[0];
  const float* w_ih0 = (const float*)d_in[1];
  const float* w_hh0 = (const float*)d_in[2];
  const float* b_ih0 = (const float*)d_in[3];
  const float* b_hh0 = (const float*)d_in[4];
  const float* w_ih1 = (const float*)d_in[5];
  const float* w_hh1 = (const float*)d_in[6];
  const float* b_ih1 = (const float*)d_in[7];
  const float* b_hh1 = (const float*)d_in[8];
  const float* fc1_w = (const float*)d_in[9];
  const float* fc1_b = (const float*)d_in[10];
  const float* fc2_w = (const float*)d_in[11];
  const float* fc2_b = (const float*)d_in[12];
  float* out = (float*)d_out;

  char* ws = (char*)d_ws;
  u32* ring0 = (u32*)(ws);                    // 4 x [256][512] u32 = 2 MB
  u32* ring1 = (u32*)(ws + (2 << 20));        // 2 MB
  int* fl0   = (int*)(ws + (4 << 20));        // 256*16 ints = 16 KB
  int* fl1   = (int*)(ws + (4 << 20) + 16384);

  // zero flags: 32 KB = 8192 u32 = 16 blocks x 512
  init_kernel<<<dim3(16), dim3(512), 0, stream>>>((u32*)(ws + (4 << 20)));
  rnn_kernel<<<dim3(96), dim3(512), 0, stream>>>(
      x, w_ih0, w_hh0, b_ih0, b_hh0, w_ih1, w_hh1, b_ih1, b_hh1,
      fc1_w, fc1_b, fc2_w, fc2_b, out, ring0, ring1, fl0, fl1);
}